// Round 6
// baseline (671.453 us; speedup 1.0000x reference)
//
#include <hip/hip_runtime.h>
#include <math.h>

// SparseEdgeEmbeddingV3: out[1, N, N, 16] fp32, N=3072.
// keep(i,j) = exp(-d2/18) >= 0.9 && d2 > 0 && i != j   (sig_max = 3.0)
// out[i,j,c] = keep ? exp(-d2 / (2*sigma_c^2)) : 0
//
// R6 = MEASUREMENT ROUND. Kernel body is byte-identical to R4 (best: 563 us).
// kernel_launch fires it TWICE back-to-back (idempotent -> still correct).
// dur_us(R6) - dur_us(R4) = true kernel duration, which three rounds of
// top-5 counters could not reveal (our dispatch always < the 380 us poison
// fills). T~90us -> kernel already at 604MB write floor (Scenario A);
// T~185us -> 2x headroom inside the kernel (Scenario B).
//
// KEEP decision numerics bit-identical to R1/R3/R4-passing kernels
// (matches numpy boundary behavior on this fixed input — do not touch):
//   sq = (x*x + y*y) + z*z  (rn, no fma)
//   dot = fma(z,z, fma(y,y, x*x))
//   d2 = max((sqi+sqj) - 2*dot, 0)
//   d2<=1.8 keep, d2>2.0 drop, band decided by f64 exp(fp32(-d2/18)) >= 0.9
// Kept VALUES only need |err| << 0.02 -> native rcp + __expf.

constexpr int N_PTS = 3072;

__global__ __launch_bounds__(256) void sparse_edge_kernel(
    const float* __restrict__ coord,   // [N,3]
    const float* __restrict__ sigma,   // [16]
    float* __restrict__ out)           // [N,N,16]
{
    const int i  = blockIdx.y;
    const int j  = (blockIdx.x << 6) + (threadIdx.x >> 2);  // 64 j per block
    const int c4 = threadIdx.x & 3;

    const float xi = coord[3 * i + 0], yi = coord[3 * i + 1], zi = coord[3 * i + 2];
    const float xj = coord[3 * j + 0], yj = coord[3 * j + 1], zj = coord[3 * j + 2];

    // --- keep decision: EXACT R1 numerics ---
    float sqi = __fadd_rn(__fadd_rn(__fmul_rn(xi, xi), __fmul_rn(yi, yi)),
                          __fmul_rn(zi, zi));
    float sqj = __fadd_rn(__fadd_rn(__fmul_rn(xj, xj), __fmul_rn(yj, yj)),
                          __fmul_rn(zj, zj));
    float dot = __fmul_rn(xi, xj);
    dot = __builtin_fmaf(yi, yj, dot);
    dot = __builtin_fmaf(zi, zj, dot);

    float d2 = __fsub_rn(__fadd_rn(sqi, sqj), __fmul_rn(2.0f, dot));
    d2 = fmaxf(d2, 0.0f);

    bool keep = (i != j) && (d2 > 0.0f) && !(d2 > 2.0f);
    if (keep && d2 > 1.8f) {
        // Rare band (~0.4% of pairs): numpy-matching arithmetic.
        float smax = sigma[15];                                  // 3.0
        float den  = __fmul_rn(__fmul_rn(2.0f, smax), smax);     // 18.0 exact
        float qf   = __fdiv_rn(-d2, den);                        // fp32 rn
        keep = (exp((double)qf) >= 0.9);
    }

    float4 v = make_float4(0.0f, 0.0f, 0.0f, 0.0f);
    if (keep) {
        const float4 s = reinterpret_cast<const float4*>(sigma)[c4];
        float i0 = __builtin_amdgcn_rcpf(2.0f * s.x * s.x);
        float i1 = __builtin_amdgcn_rcpf(2.0f * s.y * s.y);
        float i2 = __builtin_amdgcn_rcpf(2.0f * s.z * s.z);
        float i3 = __builtin_amdgcn_rcpf(2.0f * s.w * s.w);
        v.x = __expf(-d2 * i0);
        v.y = __expf(-d2 * i1);
        v.z = __expf(-d2 * i2);
        v.w = __expf(-d2 * i3);
    }

    size_t idx = ((size_t)i * N_PTS << 2) + ((size_t)blockIdx.x << 8) + threadIdx.x;
    reinterpret_cast<float4*>(out)[idx] = v;
}

extern "C" void kernel_launch(void* const* d_in, const int* in_sizes, int n_in,
                              void* d_out, int out_size, void* d_ws, size_t ws_size,
                              hipStream_t stream) {
    const float* coord = (const float*)d_in[0];   // [3072, 3] fp32
    const float* sigma = (const float*)d_in[1];   // [16] fp32
    float* out = (float*)d_out;                   // [1, 3072, 3072, 16] fp32

    dim3 grid(N_PTS / 64, N_PTS);   // (48, 3072)
    dim3 block(256);
    // Launch TWICE: second launch writes identical values (idempotent).
    // Delta vs the single-launch R4 bench isolates the kernel's true duration.
    hipLaunchKernelGGL(sparse_edge_kernel, grid, block, 0, stream,
                       coord, sigma, out);
    hipLaunchKernelGGL(sparse_edge_kernel, grid, block, 0, stream,
                       coord, sigma, out);
}

// Round 7
// 563.461 us; speedup vs baseline: 1.1917x; 1.1917x over previous
//
#include <hip/hip_runtime.h>
#include <math.h>

// SparseEdgeEmbeddingV3: out[1, N, N, 16] fp32, N=3072.
// keep(i,j) = exp(-d2/18) >= 0.9 && d2 > 0 && i != j   (sig_max = 3.0)
// out[i,j,c] = keep ? exp(-d2 / (2*sigma_c^2)) : 0
//
// FINAL (== R4, best measured). R6's double-launch probe decomposed dur_us:
//   T_kernel = 671.5 - 563.1 = 108.3 us  ->  604 MB / 108.3 us = 5.58 TB/s,
//   88% of the harness fill-kernel ceiling (6.16-6.39 TB/s); remaining
//   headroom 10-14 us ~= harness noise. Write-BW roofline reached.
// dur_us is ~455 us fixed harness poison fills + ~108 us kernel.
//
// KEEP decision numerics bit-identical to R1/R3/R4-passing kernels
// (matches numpy boundary behavior on this fixed input — do not touch):
//   sq = (x*x + y*y) + z*z  (rn, no fma)
//   dot = fma(z,z, fma(y,y, x*x))
//   d2 = max((sqi+sqj) - 2*dot, 0)
//   d2<=1.8 keep, d2>2.0 drop, band decided by f64 exp(fp32(-d2/18)) >= 0.9
// Kept VALUES only need |err| << 0.02 -> native rcp + __expf.

constexpr int N_PTS = 3072;

__global__ __launch_bounds__(256) void sparse_edge_kernel(
    const float* __restrict__ coord,   // [N,3]
    const float* __restrict__ sigma,   // [16]
    float* __restrict__ out)           // [N,N,16]
{
    const int i  = blockIdx.y;
    const int j  = (blockIdx.x << 6) + (threadIdx.x >> 2);  // 64 j per block
    const int c4 = threadIdx.x & 3;

    const float xi = coord[3 * i + 0], yi = coord[3 * i + 1], zi = coord[3 * i + 2];
    const float xj = coord[3 * j + 0], yj = coord[3 * j + 1], zj = coord[3 * j + 2];

    // --- keep decision: EXACT R1 numerics ---
    float sqi = __fadd_rn(__fadd_rn(__fmul_rn(xi, xi), __fmul_rn(yi, yi)),
                          __fmul_rn(zi, zi));
    float sqj = __fadd_rn(__fadd_rn(__fmul_rn(xj, xj), __fmul_rn(yj, yj)),
                          __fmul_rn(zj, zj));
    float dot = __fmul_rn(xi, xj);
    dot = __builtin_fmaf(yi, yj, dot);
    dot = __builtin_fmaf(zi, zj, dot);

    float d2 = __fsub_rn(__fadd_rn(sqi, sqj), __fmul_rn(2.0f, dot));
    d2 = fmaxf(d2, 0.0f);

    bool keep = (i != j) && (d2 > 0.0f) && !(d2 > 2.0f);
    if (keep && d2 > 1.8f) {
        // Rare band (~0.4% of pairs): numpy-matching arithmetic.
        float smax = sigma[15];                                  // 3.0
        float den  = __fmul_rn(__fmul_rn(2.0f, smax), smax);     // 18.0 exact
        float qf   = __fdiv_rn(-d2, den);                        // fp32 rn
        keep = (exp((double)qf) >= 0.9);
    }

    float4 v = make_float4(0.0f, 0.0f, 0.0f, 0.0f);
    if (keep) {
        const float4 s = reinterpret_cast<const float4*>(sigma)[c4];
        float i0 = __builtin_amdgcn_rcpf(2.0f * s.x * s.x);
        float i1 = __builtin_amdgcn_rcpf(2.0f * s.y * s.y);
        float i2 = __builtin_amdgcn_rcpf(2.0f * s.z * s.z);
        float i3 = __builtin_amdgcn_rcpf(2.0f * s.w * s.w);
        v.x = __expf(-d2 * i0);
        v.y = __expf(-d2 * i1);
        v.z = __expf(-d2 * i2);
        v.w = __expf(-d2 * i3);
    }

    size_t idx = ((size_t)i * N_PTS << 2) + ((size_t)blockIdx.x << 8) + threadIdx.x;
    reinterpret_cast<float4*>(out)[idx] = v;
}

extern "C" void kernel_launch(void* const* d_in, const int* in_sizes, int n_in,
                              void* d_out, int out_size, void* d_ws, size_t ws_size,
                              hipStream_t stream) {
    const float* coord = (const float*)d_in[0];   // [3072, 3] fp32
    const float* sigma = (const float*)d_in[1];   // [16] fp32
    float* out = (float*)d_out;                   // [1, 3072, 3072, 16] fp32

    dim3 grid(N_PTS / 64, N_PTS);   // (48, 3072)
    dim3 block(256);
    hipLaunchKernelGGL(sparse_edge_kernel, grid, block, 0, stream,
                       coord, sigma, out);
}